// Round 9
// baseline (234.450 us; speedup 1.0000x reference)
//
#include <hip/hip_runtime.h>

#define N_NODES 50000
#define N_EDGES 800000
#define BN_EPS 1e-5f
#define NPAD 50176          // N_NODES padded to 98*512
#define SCAN_BLOCKS 98      // 98*512 = 50176

// CSR-build tiling: 64 edge slices x 4 node ranges of 16384 bins (packed LDS counters)
#define S_SLICES 64
#define R_RANGES 4
#define BINS 16384
#define NP4 (R_RANGES * BINS)        // 65536 bins per slice
#define ES (N_EDGES / S_SLICES)      // 12500 edges per slice (div by 4)

#define XS_STRIDE 68                 // LDS row stride in uints: bank spread

#define NB_FILL (S_SLICES * R_RANGES)    // 256 count blocks

typedef unsigned int uint;
typedef unsigned short ushort;
typedef unsigned char uchar;
typedef float floatx4 __attribute__((ext_vector_type(4)));
typedef short bf16x8 __attribute__((ext_vector_type(8)));

// ---- bf16 helpers ----
__device__ __forceinline__ float bfl(uint u) { return __uint_as_float(u << 16); }
__device__ __forceinline__ float bfh(uint u) { return __uint_as_float(u & 0xffff0000u); }
__device__ __forceinline__ uint pack_bf2(float a, float b) {
    uint ua = __float_as_uint(a), ub = __float_as_uint(b);
    ua += 0x7fffu + ((ua >> 16) & 1u);   // RNE
    ub += 0x7fffu + ((ub >> 16) & 1u);
    return (ua >> 16) | (ub & 0xffff0000u);
}
__device__ __forceinline__ ushort bf1(float x) {
    uint u = __float_as_uint(x);
    u += 0x7fffu + ((u >> 16) & 1u);
    return (ushort)(u >> 16);
}
__device__ __forceinline__ void acc8(float* a, uint4 h, float w) {
    a[0] += w * bfl(h.x); a[1] += w * bfh(h.x);
    a[2] += w * bfl(h.y); a[3] += w * bfh(h.y);
    a[4] += w * bfl(h.z); a[5] += w * bfh(h.z);
    a[6] += w * bfl(h.w); a[7] += w * bfh(h.w);
}

// ---------------- count: 8-bit packed LDS histograms per (slice, range) --------------
// The atomicAdd's OLD value is the edge's slot within its (slice, src) bucket; we
// store it to eslot[] so fill needs no atomics/LDS at all (round-9 change).
// Extra block (blockIdx == NB_FILL) does the W1t/W2t bf16 transpose (fused prep_w).
__global__ __launch_bounds__(1024) void count_hist_kernel(const int* __restrict__ src,
                                                          const int* __restrict__ dst,
                                                          const float* __restrict__ W1,
                                                          const float* __restrict__ W2,
                                                          uint* __restrict__ W1t,
                                                          uint* __restrict__ W2t,
                                                          uchar* __restrict__ part_cnt,
                                                          uchar* __restrict__ part_deg,
                                                          uchar* __restrict__ eslot) {
    if (blockIdx.x == NB_FILL) {
        for (int t = threadIdx.x; t < 12288; t += 1024) {
            if (t < 8192) {
                int n = t >> 6, kk = t & 63;
                W1t[t] = pack_bf2(W1[(2 * kk) * 128 + n], W1[(2 * kk + 1) * 128 + n]);
            } else {
                int u = t - 8192;
                int n = u >> 6, kk = u & 63;
                W2t[u] = pack_bf2(W2[(2 * kk) * 64 + n], W2[(2 * kk + 1) * 64 + n]);
            }
        }
        return;
    }
    __shared__ uint cnt_lds[BINS / 4];   // 4 bins per uint (8-bit fields), 16 KB
    __shared__ uint deg_lds[BINS / 4];
    const int s = blockIdx.x / R_RANGES;
    const int r = blockIdx.x % R_RANGES;
    const int base = r * BINS;
    for (int j = threadIdx.x; j < BINS / 4; j += 1024) { cnt_lds[j] = 0u; deg_lds[j] = 0u; }
    __syncthreads();
    const int4* s4 = (const int4*)(src + s * ES);
    const int4* d4 = (const int4*)(dst + s * ES);
    uchar* es = eslot + s * ES;
    for (int g = threadIdx.x; g < ES / 4; g += 1024) {
        int4 sv = s4[g];
        int4 dv = d4[g];
#pragma unroll
        for (int k = 0; k < 4; ++k) {
            int ss = (&sv.x)[k], dd = (&dv.x)[k];
            if (ss != dd) {
                int a = ss - base;
                if ((unsigned)a < (unsigned)BINS) {
                    const int sh = (a & 3) * 8;
                    uint old = atomicAdd(&cnt_lds[a >> 2], 1u << sh);
                    es[4 * g + k] = (uchar)((old >> sh) & 0xffu);
                }
                int b = dd - base;
                if ((unsigned)b < (unsigned)BINS)
                    atomicAdd(&deg_lds[b >> 2], 1u << ((b & 3) * 8));
            }
        }
    }
    __syncthreads();
    uint* pc = (uint*)&part_cnt[s * NP4 + base];
    uint* pd = (uint*)&part_deg[s * NP4 + base];
    for (int j = threadIdx.x; j < BINS / 4; j += 1024) { pc[j] = cnt_lds[j]; pd[j] = deg_lds[j]; }
}

// ---------------- reduce partials + block-local scan (merged dinv_rowcnt + scan1) -----
__global__ __launch_bounds__(256) void reduce_scan_kernel(const uchar* __restrict__ part_deg,
                                                          const uchar* __restrict__ part_cnt,
                                                          float* __restrict__ dinv,
                                                          int* __restrict__ rowcnt,
                                                          int* __restrict__ rowptr,
                                                          int* __restrict__ psum,
                                                          float* __restrict__ stats) {
    const int t = threadIdx.x;
    if (blockIdx.x == 0) stats[t] = 0.f;   // sum[128] + sumsq[128]
    const int i = blockIdx.x * 512 + 2 * t;
    uint dg0 = 0, dg1 = 0, rc0 = 0, rc1 = 0;
#pragma unroll 8
    for (int s = 0; s < S_SLICES; ++s) {
        uint vd = *(const ushort*)&part_deg[s * NP4 + i];
        uint vc = *(const ushort*)&part_cnt[s * NP4 + i];
        dg0 += vd & 0xffu; dg1 += vd >> 8;
        rc0 += vc & 0xffu; rc1 += vc >> 8;
    }
    *(int2*)&rowcnt[i] = make_int2((int)rc0, (int)rc1);
    if (i < N_NODES) dinv[i] = rsqrtf((float)dg0 + 1.0f);
    if (i + 1 < N_NODES) dinv[i + 1] = rsqrtf((float)dg1 + 1.0f);

    __shared__ int bs[256];
    const int pair = (int)(rc0 + rc1);
    bs[t] = pair;
    __syncthreads();
#pragma unroll
    for (int off = 1; off < 256; off <<= 1) {
        int x = (t >= off) ? bs[t - off] : 0;
        __syncthreads();
        bs[t] += x;
        __syncthreads();
    }
    const int excl = bs[t] - pair;
    *(int2*)&rowptr[i] = make_int2(excl + (int)rc0, excl + pair);
    if (t == 255) psum[blockIdx.x] = bs[255];
}

// ---------------- finalize rowptr (exclusive) + per-(slice,node) ushort prefixes -----
// pre[s][node] = sum_{s'<s} part_cnt[s'][node] (fits 16 bits: max degree << 65536).
__global__ __launch_bounds__(256) void cursor_init_kernel(const int* __restrict__ rowcnt,
                                                          int* __restrict__ rowptr,
                                                          const int* __restrict__ psum,
                                                          const uchar* __restrict__ part_cnt,
                                                          ushort* __restrict__ pre) {
    __shared__ int pbuf[SCAN_BLOCKS];
    __shared__ int lps;
    const int t = threadIdx.x;
    if (t < SCAN_BLOCKS) pbuf[t] = psum[t];
    __syncthreads();
    if (t == 0) {
        int acc = 0;
        for (int j = 0; j < (int)blockIdx.x; ++j) acc += pbuf[j];
        lps = acc;
    }
    __syncthreads();
    const int ps = lps;
    const int i = blockIdx.x * 512 + 2 * t;
    int b0 = rowptr[i] - rowcnt[i] + ps;
    int b1 = rowptr[i + 1] - rowcnt[i + 1] + ps;
    *(int2*)&rowptr[i] = make_int2(b0, b1);
    uint p0 = 0, p1 = 0;
#pragma unroll 8
    for (int s = 0; s < S_SLICES; ++s) {
        *(ushort2*)&pre[s * NP4 + i] = make_ushort2((ushort)p0, (ushort)p1);
        uint vc = *(const ushort*)&part_cnt[s * NP4 + i];
        p0 += vc & 0xffu;
        p1 += vc >> 8;
    }
}

// ---------------- fill CSR: pure scatter, no LDS / atomics / barriers ----------------
// pos = rowptr[src] + pre[slice][src] + eslot[edge]; edst[pos] = dst.
// rowptr (200 KB) and the per-slice pre window (128 KB) are L2-resident gathers;
// edges + eslot are streamed. Replaces the 64 KB-LDS cursor kernel (round-9).
__global__ __launch_bounds__(1024) void fill_scatter_kernel(const int* __restrict__ src,
                                                            const int* __restrict__ dst,
                                                            const int* __restrict__ rowptr,
                                                            const ushort* __restrict__ pre,
                                                            const uchar* __restrict__ eslot,
                                                            int* __restrict__ edst) {
    const int nq = N_EDGES / 4;
    for (int q = blockIdx.x * 1024 + threadIdx.x; q < nq; q += gridDim.x * 1024) {
        int4 sv = ((const int4*)src)[q];
        int4 dv = ((const int4*)dst)[q];
        uint sl4 = *(const uint*)&eslot[4 * q];
        const int s = (4 * q) / ES;          // slice (uniform per int4: ES % 4 == 0)
        const ushort* pr = &pre[s * NP4];
#pragma unroll
        for (int k = 0; k < 4; ++k) {
            int ss = (&sv.x)[k], dd = (&dv.x)[k];
            if (ss != dd) {
                int pos = rowptr[ss] + (int)pr[ss] + (int)((sl4 >> (8 * k)) & 0xffu);
                edst[pos] = dd;
            }
        }
    }
}

// ---------------- GEMM1 (MFMA): Hbf = bf16(X @ W1 + b1), 64-row tiles ----------------
__global__ __launch_bounds__(256) void gemm1_mfma_kernel(const float* __restrict__ X,
                                                         const uint* __restrict__ W1t,
                                                         const float* __restrict__ bias,
                                                         ushort* __restrict__ Hbf) {
    __shared__ uint lds[(64 + 128) * XS_STRIDE];
    uint* Xs = lds;
    uint* Ws = lds + 64 * XS_STRIDE;
    const int t = threadIdx.x;
    const int rowBase = blockIdx.x * 64;

    {
        int r = t >> 2, q = t & 3;
        int arow = rowBase + r;
        uint* xd = &Xs[r * XS_STRIDE + q * 16];
        if (arow < N_NODES) {
            const float4* xp = (const float4*)&X[arow * 128 + q * 32];
#pragma unroll
            for (int i = 0; i < 8; ++i) {
                float4 v = xp[i];
                xd[2 * i]     = pack_bf2(v.x, v.y);
                xd[2 * i + 1] = pack_bf2(v.z, v.w);
            }
        } else {
#pragma unroll
            for (int i = 0; i < 16; ++i) xd[i] = 0u;
        }
    }
    {
        int n = t >> 1, half = t & 1;
        const uint4* wp = (const uint4*)&W1t[n * 64 + half * 32];
        uint* wd = &Ws[n * XS_STRIDE + half * 32];
#pragma unroll
        for (int i = 0; i < 8; ++i) *(uint4*)&wd[i * 4] = wp[i];
    }
    __syncthreads();

    const int wv = t >> 6, lane = t & 63;
    const int lr = lane & 15;
    const int ko = (lane >> 4) * 4;
    const int m0 = wv * 16;
    floatx4 acc[8];
#pragma unroll
    for (int j = 0; j < 8; ++j) acc[j] = (floatx4){0.f, 0.f, 0.f, 0.f};

#pragma unroll
    for (int ks = 0; ks < 4; ++ks) {
        const int kb = ks * 16 + ko;
        bf16x8 a = *(bf16x8*)&Xs[(m0 + lr) * XS_STRIDE + kb];
#pragma unroll
        for (int j = 0; j < 8; ++j) {
            bf16x8 b = *(bf16x8*)&Ws[(j * 16 + lr) * XS_STRIDE + kb];
            acc[j] = __builtin_amdgcn_mfma_f32_16x16x32_bf16(a, b, acc[j], 0, 0, 0);
        }
    }
    const int rbase = rowBase + m0 + (lane >> 4) * 4;
#pragma unroll
    for (int j = 0; j < 8; ++j) {
        const int col = j * 16 + lr;
        const float bb = bias[col];
#pragma unroll
        for (int r = 0; r < 4; ++r) {
            int row = rbase + r;
            if (row < N_NODES) Hbf[row * 128 + col] = bf1(acc[j][r] + bb);
        }
    }
}

// ---------------- GEMM2 (MFMA): Hbf = bf16(relu(bn(bf16 Hin)) @ W2 + b2) ------------
__global__ __launch_bounds__(256) void gemm2_mfma_kernel(const uint* __restrict__ Hin,
                                                         const uint* __restrict__ W2t,
                                                         const float* __restrict__ bias,
                                                         const float* __restrict__ sum,
                                                         const float* __restrict__ sumsq,
                                                         const float* __restrict__ gamma,
                                                         const float* __restrict__ beta,
                                                         ushort* __restrict__ Hbf) {
    __shared__ uint lds[(64 + 64) * XS_STRIDE];
    __shared__ float sc_sh[128], sh_sh[128];
    uint* Xs = lds;
    uint* Ws = lds + 64 * XS_STRIDE;
    const int t = threadIdx.x;
    const int rowBase = blockIdx.x * 64;

    if (t < 128) {
        float mean = sum[t] * (1.0f / N_NODES);
        float var = sumsq[t] * (1.0f / N_NODES) - mean * mean;
        float sc = gamma[t] * rsqrtf(var + BN_EPS);
        sc_sh[t] = sc;
        sh_sh[t] = beta[t] - mean * sc;
    }
    if (t >= 128) {
        int u = t - 128;
        int n = u >> 1, half = u & 1;
        const uint4* wp = (const uint4*)&W2t[n * 64 + half * 32];
        uint* wd = &Ws[n * XS_STRIDE + half * 32];
#pragma unroll
        for (int i = 0; i < 8; ++i) *(uint4*)&wd[i * 4] = wp[i];
    }
    __syncthreads();

    {
        int r = t >> 2, q = t & 3;
        int arow = rowBase + r;
        uint* xd = &Xs[r * XS_STRIDE + q * 16];
        if (arow < N_NODES) {
            const uint* hp = &Hin[arow * 64 + q * 16];
#pragma unroll
            for (int i = 0; i < 16; ++i) {
                uint u = hp[i];
                int m = q * 16 + i;
                float a0 = fmaxf(0.f, bfl(u) * sc_sh[2 * m] + sh_sh[2 * m]);
                float a1 = fmaxf(0.f, bfh(u) * sc_sh[2 * m + 1] + sh_sh[2 * m + 1]);
                xd[i] = pack_bf2(a0, a1);
            }
        } else {
#pragma unroll
            for (int i = 0; i < 16; ++i) xd[i] = 0u;
        }
    }
    __syncthreads();

    const int wv = t >> 6, lane = t & 63;
    const int lr = lane & 15;
    const int ko = (lane >> 4) * 4;
    const int m0 = wv * 16;
    floatx4 acc[4];
#pragma unroll
    for (int j = 0; j < 4; ++j) acc[j] = (floatx4){0.f, 0.f, 0.f, 0.f};

#pragma unroll
    for (int ks = 0; ks < 4; ++ks) {
        const int kb = ks * 16 + ko;
        bf16x8 a = *(bf16x8*)&Xs[(m0 + lr) * XS_STRIDE + kb];
#pragma unroll
        for (int j = 0; j < 4; ++j) {
            bf16x8 b = *(bf16x8*)&Ws[(j * 16 + lr) * XS_STRIDE + kb];
            acc[j] = __builtin_amdgcn_mfma_f32_16x16x32_bf16(a, b, acc[j], 0, 0, 0);
        }
    }
    const int rbase = rowBase + m0 + (lane >> 4) * 4;
#pragma unroll
    for (int j = 0; j < 4; ++j) {
        const int col = j * 16 + lr;
        const float bb = bias[col];
#pragma unroll
        for (int r = 0; r < 4; ++r) {
            int row = rbase + r;
            if (row < N_NODES) Hbf[row * 64 + col] = bf1(acc[j][r] + bb);
        }
    }
}

// ---------------- CSR gather SpMM, 4 edge-groups per row, weight-on-the-fly ----------
// out[row] = dinv[row] * ( dinv[row]*H[row] + sum_e dinv[dst]*H[dst] ).
// Each row is handled by 4*LPR lanes: group g takes edges e0+g, e0+g+4, ... (scalar,
// uniform per group); per iter 4 gathers in flight per lane. Partials combined with
// two shfl_xor steps (LPR, 2*LPR) — no LDS, no barrier. Grids divide N exactly.
template <int C, bool OUT_BF16>
__global__ __launch_bounds__(256) void spmm_bf16_kernel(const int* __restrict__ rowptr,
                                                        const int* __restrict__ edst,
                                                        const float* __restrict__ dinv,
                                                        const uint* __restrict__ H,
                                                        void* __restrict__ outv) {
    constexpr int LPR = C / 8;        // data lanes per row
    constexpr int TPR = LPR * 4;      // threads per row (4 edge groups)
    constexpr int RPB = 256 / TPR;    // rows per block
    constexpr int US  = C / 2;        // uint row stride
    const int t = threadIdx.x;
    const int lane = t % LPR;
    const int g = (t / LPR) & 3;      // edge group
    const int row = blockIdx.x * RPB + t / TPR;
    const int cu = lane * 4;
    const float di = dinv[row];

    float acc[8];
#pragma unroll
    for (int j = 0; j < 8; ++j) acc[j] = 0.f;
    if (g == 0) {                      // self term, pre-scaled by 1/di
        uint4 hv = *(const uint4*)&H[row * US + cu];
        acc8(acc, hv, di);
    }
    const int e0 = rowptr[row], e1 = rowptr[row + 1];
    int e = e0 + g;
    for (; e + 12 < e1; e += 16) {     // 4 edges per group per iter
        int d0 = edst[e], d1 = edst[e + 4], d2 = edst[e + 8], d3 = edst[e + 12];
        float w0 = dinv[d0], w1 = dinv[d1], w2 = dinv[d2], w3 = dinv[d3];
        uint4 h0 = *(const uint4*)&H[d0 * US + cu];
        uint4 h1 = *(const uint4*)&H[d1 * US + cu];
        uint4 h2 = *(const uint4*)&H[d2 * US + cu];
        uint4 h3 = *(const uint4*)&H[d3 * US + cu];
        acc8(acc, h0, w0);
        acc8(acc, h1, w1);
        acc8(acc, h2, w2);
        acc8(acc, h3, w3);
    }
    for (; e < e1; e += 4) {
        int d = edst[e];
        float w = dinv[d];
        uint4 h = *(const uint4*)&H[d * US + cu];
        acc8(acc, h, w);
    }
    // combine the four edge groups (tree over lane^LPR then lane^2LPR)
#pragma unroll
    for (int j = 0; j < 8; ++j) acc[j] += __shfl_xor(acc[j], LPR, 64);
#pragma unroll
    for (int j = 0; j < 8; ++j) acc[j] += __shfl_xor(acc[j], 2 * LPR, 64);
    if (g != 0) return;
    if (OUT_BF16) {
        uint4 o;
        o.x = pack_bf2(acc[0] * di, acc[1] * di);
        o.y = pack_bf2(acc[2] * di, acc[3] * di);
        o.z = pack_bf2(acc[4] * di, acc[5] * di);
        o.w = pack_bf2(acc[6] * di, acc[7] * di);
        *(uint4*)&((uint*)outv)[row * US + cu] = o;
    } else {
        float* out = (float*)outv;
        *(float4*)&out[row * C + lane * 8] =
            make_float4(acc[0] * di, acc[1] * di, acc[2] * di, acc[3] * di);
        *(float4*)&out[row * C + lane * 8 + 4] =
            make_float4(acc[4] * di, acc[5] * di, acc[6] * di, acc[7] * di);
    }
}

// ---------------- BN statistics over bf16 h1agg ----------------
__global__ __launch_bounds__(256) void bn_stats_kernel(const uint* __restrict__ H,
                                                       float* __restrict__ sum,
                                                       float* __restrict__ sumsq) {
    int uc = threadIdx.x & 63;       // uint column (2 channels)
    int quarter = threadIdx.x >> 6;
    const int stride = gridDim.x * 4;
    float s0 = 0.f, q0 = 0.f, s1 = 0.f, q1 = 0.f;
    for (int r = blockIdx.x * 4 + quarter; r < N_NODES; r += stride) {
        uint u = H[r * 64 + uc];
        float a = bfl(u), b = bfh(u);
        s0 += a; q0 += a * a;
        s1 += b; q1 += b * b;
    }
    __shared__ float red[4][256];
    red[0][threadIdx.x] = s0; red[1][threadIdx.x] = q0;
    red[2][threadIdx.x] = s1; red[3][threadIdx.x] = q1;
    __syncthreads();
    if (quarter == 0) {
        float ts0 = 0.f, tq0 = 0.f, ts1 = 0.f, tq1 = 0.f;
#pragma unroll
        for (int k = 0; k < 4; ++k) {
            ts0 += red[0][k * 64 + uc]; tq0 += red[1][k * 64 + uc];
            ts1 += red[2][k * 64 + uc]; tq1 += red[3][k * 64 + uc];
        }
        atomicAdd(&sum[2 * uc], ts0);
        atomicAdd(&sum[2 * uc + 1], ts1);
        atomicAdd(&sumsq[2 * uc], tq0);
        atomicAdd(&sumsq[2 * uc + 1], tq1);
    }
}

extern "C" void kernel_launch(void* const* d_in, const int* in_sizes, int n_in,
                              void* d_out, int out_size, void* d_ws, size_t ws_size,
                              hipStream_t stream) {
    const float* x     = (const float*)d_in[0];
    const int*   ei    = (const int*)d_in[1];
    const float* W1    = (const float*)d_in[2];
    const float* b1    = (const float*)d_in[3];
    const float* gamma = (const float*)d_in[4];
    const float* beta  = (const float*)d_in[5];
    const float* W2    = (const float*)d_in[6];
    const float* b2    = (const float*)d_in[7];
    float* out = (float*)d_out;
    const int* src = ei;
    const int* dst = ei + N_EDGES;

    // ---- workspace layout (4-byte words) ----
    float* ws     = (float*)d_ws;
    float* dinv   = ws;                              // NPAD
    float* stats  = ws + NPAD;                       // 256 (sum 128 + sumsq 128)
    int*   psum   = (int*)(ws + NPAD + 512);         // 128
    int*   rowcnt = psum + 128;                      // NPAD
    int*   rowptr = rowcnt + NPAD;                   // NPAD
    float* big    = (float*)(rowptr + NPAD);
    // BIG region (word offsets), lifetime-disjoint aliases:
    //   edst     @ 0         [0.8M]     (fill -> spmms; dst-only, 4 B/edge)
    //   part_cnt @ 1.6M      [1.05M]    (8-bit; dead after cursor_init)
    //   part_deg @ 3.7M      [1.05M]    (8-bit; dead after reduce_scan)
    //   pre      @ 5.8M      [2.1M]     (ushort prefixes; dead after fill)
    //   eslot    @ 8.2M      [0.2M]     (8-bit slots, count -> fill)
    //   h1bf     @ 1.6M      [3.2M]     (gemm1 -> spmm1; aliases part arrays, dead by then)
    //   h1agg    @ 4.8M      [3.2M]     (spmm1 bf16 out; overlaps pre tail, dead by then)
    //   W1t/W2t  @ 10.0M     [12K]
    int*    edst     = (int*)big;
    uchar*  part_cnt = (uchar*)(big + 1600000);
    uchar*  part_deg = (uchar*)(big + 3700000);
    ushort* pre      = (ushort*)(big + 5800000);
    uchar*  eslot    = (uchar*)(big + 8200000);
    ushort* h1bf     = (ushort*)(big + 1600000);
    uint*   h1agg    = (uint*)(big + 4800000);       // bf16 x128, packed pairs
    ushort* h2bf     = h1bf;                         // 64ch, fits in h1bf region
    uint*   W1t      = (uint*)(big + 10000000);
    uint*   W2t      = W1t + 8192;
    float* sum    = stats;
    float* sumsq  = stats + 128;

    count_hist_kernel<<<NB_FILL + 1, 1024, 0, stream>>>(src, dst, W1, W2, W1t, W2t,
                                                        part_cnt, part_deg, eslot);
    reduce_scan_kernel<<<SCAN_BLOCKS, 256, 0, stream>>>(part_deg, part_cnt, dinv, rowcnt,
                                                        rowptr, psum, stats);
    cursor_init_kernel<<<SCAN_BLOCKS, 256, 0, stream>>>(rowcnt, rowptr, psum, part_cnt, pre);
    fill_scatter_kernel<<<256, 1024, 0, stream>>>(src, dst, rowptr, pre, eslot, edst);

    gemm1_mfma_kernel<<<(N_NODES + 63) / 64, 256, 0, stream>>>(x, W1t, b1, h1bf);

    spmm_bf16_kernel<128, true><<<N_NODES / 4, 256, 0, stream>>>(
        rowptr, edst, dinv, (const uint*)h1bf, (void*)h1agg);

    bn_stats_kernel<<<250, 256, 0, stream>>>(h1agg, sum, sumsq);

    gemm2_mfma_kernel<<<(N_NODES + 63) / 64, 256, 0, stream>>>(h1agg, W2t, b2, sum, sumsq,
                                                               gamma, beta, h2bf);

    spmm_bf16_kernel<64, false><<<N_NODES / 8, 256, 0, stream>>>(
        rowptr, edst, dinv, (const uint*)h2bf, (void*)out);
}

// Round 11
// 223.305 us; speedup vs baseline: 1.0499x; 1.0499x over previous
//
#include <hip/hip_runtime.h>

#define N_NODES 50000
#define N_EDGES 800000
#define BN_EPS 1e-5f
#define NPAD 50176          // N_NODES padded to 98*512
#define SCAN_BLOCKS 98      // 98*512 = 50176

// CSR-build tiling: 64 edge slices x 4 node ranges of 16384 bins (packed LDS counters)
#define S_SLICES 64
#define R_RANGES 4
#define BINS 16384
#define NP4 (R_RANGES * BINS)        // 65536 bins per slice
#define ES (N_EDGES / S_SLICES)      // 12500 edges per slice (div by 4)

#define XS_STRIDE 68                 // LDS row stride in uints: bank spread

#define NB_FILL (S_SLICES * R_RANGES)    // 256 count/fill blocks
#define NB_G1   ((N_NODES + 63) / 64)    // 782 gemm1 blocks

typedef unsigned int uint;
typedef unsigned short ushort;
typedef unsigned char uchar;
typedef float floatx4 __attribute__((ext_vector_type(4)));
typedef short bf16x8 __attribute__((ext_vector_type(8)));

// ---- bf16 helpers ----
__device__ __forceinline__ float bfl(uint u) { return __uint_as_float(u << 16); }
__device__ __forceinline__ float bfh(uint u) { return __uint_as_float(u & 0xffff0000u); }
__device__ __forceinline__ uint pack_bf2(float a, float b) {
    uint ua = __float_as_uint(a), ub = __float_as_uint(b);
    ua += 0x7fffu + ((ua >> 16) & 1u);   // RNE
    ub += 0x7fffu + ((ub >> 16) & 1u);
    return (ua >> 16) | (ub & 0xffff0000u);
}
__device__ __forceinline__ ushort bf1(float x) {
    uint u = __float_as_uint(x);
    u += 0x7fffu + ((u >> 16) & 1u);
    return (ushort)(u >> 16);
}
__device__ __forceinline__ void acc8(float* a, uint4 h, float w) {
    a[0] += w * bfl(h.x); a[1] += w * bfh(h.x);
    a[2] += w * bfl(h.y); a[3] += w * bfh(h.y);
    a[4] += w * bfl(h.z); a[5] += w * bfh(h.z);
    a[6] += w * bfl(h.w); a[7] += w * bfh(h.w);
}

// ---------------- count: 8-bit packed LDS histograms per (slice, range) --------------
// 1024-thread blocks: 16 waves/CU on a latency-bound atomic kernel.
// Extra block (blockIdx == NB_FILL) does the W1t/W2t bf16 transpose (fused prep_w).
__global__ __launch_bounds__(1024) void count_hist_kernel(const int* __restrict__ src,
                                                          const int* __restrict__ dst,
                                                          const float* __restrict__ W1,
                                                          const float* __restrict__ W2,
                                                          uint* __restrict__ W1t,
                                                          uint* __restrict__ W2t,
                                                          uchar* __restrict__ part_cnt,
                                                          uchar* __restrict__ part_deg) {
    if (blockIdx.x == NB_FILL) {
        for (int t = threadIdx.x; t < 12288; t += 1024) {
            if (t < 8192) {
                int n = t >> 6, kk = t & 63;
                W1t[t] = pack_bf2(W1[(2 * kk) * 128 + n], W1[(2 * kk + 1) * 128 + n]);
            } else {
                int u = t - 8192;
                int n = u >> 6, kk = u & 63;
                W2t[u] = pack_bf2(W2[(2 * kk) * 64 + n], W2[(2 * kk + 1) * 64 + n]);
            }
        }
        return;
    }
    __shared__ uint cnt_lds[BINS / 4];   // 4 bins per uint (8-bit fields), 16 KB
    __shared__ uint deg_lds[BINS / 4];
    const int s = blockIdx.x / R_RANGES;
    const int r = blockIdx.x % R_RANGES;
    const int base = r * BINS;
    for (int j = threadIdx.x; j < BINS / 4; j += 1024) { cnt_lds[j] = 0u; deg_lds[j] = 0u; }
    __syncthreads();
    const int4* s4 = (const int4*)(src + s * ES);
    const int4* d4 = (const int4*)(dst + s * ES);
    for (int g = threadIdx.x; g < ES / 4; g += 1024) {
        int4 sv = s4[g];
        int4 dv = d4[g];
#pragma unroll
        for (int k = 0; k < 4; ++k) {
            int ss = (&sv.x)[k], dd = (&dv.x)[k];
            if (ss != dd) {
                int a = ss - base;
                if ((unsigned)a < (unsigned)BINS)
                    atomicAdd(&cnt_lds[a >> 2], 1u << ((a & 3) * 8));
                int b = dd - base;
                if ((unsigned)b < (unsigned)BINS)
                    atomicAdd(&deg_lds[b >> 2], 1u << ((b & 3) * 8));
            }
        }
    }
    __syncthreads();
    uint* pc = (uint*)&part_cnt[s * NP4 + base];
    uint* pd = (uint*)&part_deg[s * NP4 + base];
    for (int j = threadIdx.x; j < BINS / 4; j += 1024) { pc[j] = cnt_lds[j]; pd[j] = deg_lds[j]; }
}

// ---------------- reduce partials + block-local scan (merged dinv_rowcnt + scan1) -----
__global__ __launch_bounds__(256) void reduce_scan_kernel(const uchar* __restrict__ part_deg,
                                                          const uchar* __restrict__ part_cnt,
                                                          float* __restrict__ dinv,
                                                          int* __restrict__ rowcnt,
                                                          int* __restrict__ rowptr,
                                                          int* __restrict__ psum,
                                                          float* __restrict__ stats) {
    const int t = threadIdx.x;
    if (blockIdx.x == 0) stats[t] = 0.f;   // sum[128] + sumsq[128]
    const int i = blockIdx.x * 512 + 2 * t;
    uint dg0 = 0, dg1 = 0, rc0 = 0, rc1 = 0;
#pragma unroll 8
    for (int s = 0; s < S_SLICES; ++s) {
        uint vd = *(const ushort*)&part_deg[s * NP4 + i];
        uint vc = *(const ushort*)&part_cnt[s * NP4 + i];
        dg0 += vd & 0xffu; dg1 += vd >> 8;
        rc0 += vc & 0xffu; rc1 += vc >> 8;
    }
    *(int2*)&rowcnt[i] = make_int2((int)rc0, (int)rc1);
    if (i < N_NODES) dinv[i] = rsqrtf((float)dg0 + 1.0f);
    if (i + 1 < N_NODES) dinv[i + 1] = rsqrtf((float)dg1 + 1.0f);

    __shared__ int bs[256];
    const int pair = (int)(rc0 + rc1);
    bs[t] = pair;
    __syncthreads();
#pragma unroll
    for (int off = 1; off < 256; off <<= 1) {
        int x = (t >= off) ? bs[t - off] : 0;
        __syncthreads();
        bs[t] += x;
        __syncthreads();
    }
    const int excl = bs[t] - pair;
    *(int2*)&rowptr[i] = make_int2(excl + (int)rc0, excl + pair);
    if (t == 255) psum[blockIdx.x] = bs[255];
}

// ---------------- fused: cursor_init (blocks < SCAN_BLOCKS) + GEMM1 (rest) ----------
// Legal fusion: gemm1 depends only on X/W1t/b1 (ready since count); the block families
// touch DISJOINT buffers (h1bf relocated to a virgin region — round-10's crash was
// h1bf aliasing part_cnt, which cursor blocks read concurrently). Both 256-thread,
// LDS <= 52 KB (same 3 blocks/CU gemm1 had standalone).
__global__ __launch_bounds__(256) void cursor_gemm1_kernel(const int* __restrict__ rowcnt,
                                                           int* __restrict__ rowptr,
                                                           const int* __restrict__ psum,
                                                           const uchar* __restrict__ part_cnt,
                                                           ushort* __restrict__ pre,
                                                           const float* __restrict__ X,
                                                           const uint* __restrict__ W1t,
                                                           const float* __restrict__ bias,
                                                           ushort* __restrict__ Hbf) {
    __shared__ uint smem[(64 + 128) * XS_STRIDE];   // gemm1 Xs+Ws; cursor uses a corner
    const int t = threadIdx.x;

    if (blockIdx.x < SCAN_BLOCKS) {
        // ---- cursor_init: finalize rowptr (exclusive) + per-(slice,node) prefixes ----
        int* pbuf = (int*)smem;            // [SCAN_BLOCKS]
        int* lps  = pbuf + SCAN_BLOCKS;
        if (t < SCAN_BLOCKS) pbuf[t] = psum[t];
        __syncthreads();
        if (t == 0) {
            int acc = 0;
            for (int j = 0; j < (int)blockIdx.x; ++j) acc += pbuf[j];
            *lps = acc;
        }
        __syncthreads();
        const int ps = *lps;
        const int i = blockIdx.x * 512 + 2 * t;
        int b0 = rowptr[i] - rowcnt[i] + ps;
        int b1 = rowptr[i + 1] - rowcnt[i + 1] + ps;
        *(int2*)&rowptr[i] = make_int2(b0, b1);
        uint p0 = 0, p1 = 0;
#pragma unroll 8
        for (int s = 0; s < S_SLICES; ++s) {
            *(ushort2*)&pre[s * NP4 + i] = make_ushort2((ushort)p0, (ushort)p1);
            uint vc = *(const ushort*)&part_cnt[s * NP4 + i];
            p0 += vc & 0xffu;
            p1 += vc >> 8;
        }
        return;
    }

    // ---- GEMM1: Hbf = bf16(X @ W1 + b1), 64-row tiles ----
    uint* Xs = smem;
    uint* Ws = smem + 64 * XS_STRIDE;
    const int rowBase = (blockIdx.x - SCAN_BLOCKS) * 64;

    {
        int r = t >> 2, q = t & 3;
        int arow = rowBase + r;
        uint* xd = &Xs[r * XS_STRIDE + q * 16];
        if (arow < N_NODES) {
            const float4* xp = (const float4*)&X[arow * 128 + q * 32];
#pragma unroll
            for (int i = 0; i < 8; ++i) {
                float4 v = xp[i];
                xd[2 * i]     = pack_bf2(v.x, v.y);
                xd[2 * i + 1] = pack_bf2(v.z, v.w);
            }
        } else {
#pragma unroll
            for (int i = 0; i < 16; ++i) xd[i] = 0u;
        }
    }
    {
        int n = t >> 1, half = t & 1;
        const uint4* wp = (const uint4*)&W1t[n * 64 + half * 32];
        uint* wd = &Ws[n * XS_STRIDE + half * 32];
#pragma unroll
        for (int i = 0; i < 8; ++i) *(uint4*)&wd[i * 4] = wp[i];
    }
    __syncthreads();

    const int wv = t >> 6, lane = t & 63;
    const int lr = lane & 15;
    const int ko = (lane >> 4) * 4;
    const int m0 = wv * 16;
    floatx4 acc[8];
#pragma unroll
    for (int j = 0; j < 8; ++j) acc[j] = (floatx4){0.f, 0.f, 0.f, 0.f};

#pragma unroll
    for (int ks = 0; ks < 4; ++ks) {
        const int kb = ks * 16 + ko;
        bf16x8 a = *(bf16x8*)&Xs[(m0 + lr) * XS_STRIDE + kb];
#pragma unroll
        for (int j = 0; j < 8; ++j) {
            bf16x8 b = *(bf16x8*)&Ws[(j * 16 + lr) * XS_STRIDE + kb];
            acc[j] = __builtin_amdgcn_mfma_f32_16x16x32_bf16(a, b, acc[j], 0, 0, 0);
        }
    }
    const int rbase = rowBase + m0 + (lane >> 4) * 4;
#pragma unroll
    for (int j = 0; j < 8; ++j) {
        const int col = j * 16 + lr;
        const float bb = bias[col];
#pragma unroll
        for (int r = 0; r < 4; ++r) {
            int row = rbase + r;
            if (row < N_NODES) Hbf[row * 128 + col] = bf1(acc[j][r] + bb);
        }
    }
}

// ---------------- fill CSR via LDS cursors (cursor = rowptr + pre), 1024 threads -----
__global__ __launch_bounds__(1024) void fill_lds_kernel(const int* __restrict__ src,
                                                        const int* __restrict__ dst,
                                                        const int* __restrict__ rowptr,
                                                        const ushort* __restrict__ pre,
                                                        int* __restrict__ edst) {
    __shared__ int curs[BINS];   // 64 KB
    const int t = threadIdx.x;
    const int s = blockIdx.x / R_RANGES;
    const int r = blockIdx.x % R_RANGES;
    const int base = r * BINS;
    const ushort* pr = &pre[s * NP4 + base];
    for (int j = t; j < BINS; j += 1024) {
        int node = base + j;
        int rp = (node < NPAD) ? rowptr[node] : 0;   // ids >= N_NODES never occur
        curs[j] = rp + (int)pr[j];
    }
    __syncthreads();
    const int4* s4 = (const int4*)(src + s * ES);
    const int4* d4 = (const int4*)(dst + s * ES);
    for (int g = t; g < ES / 4; g += 1024) {
        int4 sv = s4[g];
        int4 dv = d4[g];
#pragma unroll
        for (int k = 0; k < 4; ++k) {
            int ss = (&sv.x)[k], dd = (&dv.x)[k];
            int a = ss - base;
            if (ss != dd && (unsigned)a < (unsigned)BINS) {
                int pos = atomicAdd(&curs[a], 1);
                edst[pos] = dd;
            }
        }
    }
}

// ---------------- GEMM2 (MFMA): Hbf = bf16(relu(bn(bf16 Hin)) @ W2 + b2) ------------
__global__ __launch_bounds__(256) void gemm2_mfma_kernel(const uint* __restrict__ Hin,
                                                         const uint* __restrict__ W2t,
                                                         const float* __restrict__ bias,
                                                         const float* __restrict__ sum,
                                                         const float* __restrict__ sumsq,
                                                         const float* __restrict__ gamma,
                                                         const float* __restrict__ beta,
                                                         ushort* __restrict__ Hbf) {
    __shared__ uint lds[(64 + 64) * XS_STRIDE];
    __shared__ float sc_sh[128], sh_sh[128];
    uint* Xs = lds;
    uint* Ws = lds + 64 * XS_STRIDE;
    const int t = threadIdx.x;
    const int rowBase = blockIdx.x * 64;

    if (t < 128) {
        float mean = sum[t] * (1.0f / N_NODES);
        float var = sumsq[t] * (1.0f / N_NODES) - mean * mean;
        float sc = gamma[t] * rsqrtf(var + BN_EPS);
        sc_sh[t] = sc;
        sh_sh[t] = beta[t] - mean * sc;
    }
    if (t >= 128) {
        int u = t - 128;
        int n = u >> 1, half = u & 1;
        const uint4* wp = (const uint4*)&W2t[n * 64 + half * 32];
        uint* wd = &Ws[n * XS_STRIDE + half * 32];
#pragma unroll
        for (int i = 0; i < 8; ++i) *(uint4*)&wd[i * 4] = wp[i];
    }
    __syncthreads();

    {
        int r = t >> 2, q = t & 3;
        int arow = rowBase + r;
        uint* xd = &Xs[r * XS_STRIDE + q * 16];
        if (arow < N_NODES) {
            const uint* hp = &Hin[arow * 64 + q * 16];
#pragma unroll
            for (int i = 0; i < 16; ++i) {
                uint u = hp[i];
                int m = q * 16 + i;
                float a0 = fmaxf(0.f, bfl(u) * sc_sh[2 * m] + sh_sh[2 * m]);
                float a1 = fmaxf(0.f, bfh(u) * sc_sh[2 * m + 1] + sh_sh[2 * m + 1]);
                xd[i] = pack_bf2(a0, a1);
            }
        } else {
#pragma unroll
            for (int i = 0; i < 16; ++i) xd[i] = 0u;
        }
    }
    __syncthreads();

    const int wv = t >> 6, lane = t & 63;
    const int lr = lane & 15;
    const int ko = (lane >> 4) * 4;
    const int m0 = wv * 16;
    floatx4 acc[4];
#pragma unroll
    for (int j = 0; j < 4; ++j) acc[j] = (floatx4){0.f, 0.f, 0.f, 0.f};

#pragma unroll
    for (int ks = 0; ks < 4; ++ks) {
        const int kb = ks * 16 + ko;
        bf16x8 a = *(bf16x8*)&Xs[(m0 + lr) * XS_STRIDE + kb];
#pragma unroll
        for (int j = 0; j < 4; ++j) {
            bf16x8 b = *(bf16x8*)&Ws[(j * 16 + lr) * XS_STRIDE + kb];
            acc[j] = __builtin_amdgcn_mfma_f32_16x16x32_bf16(a, b, acc[j], 0, 0, 0);
        }
    }
    const int rbase = rowBase + m0 + (lane >> 4) * 4;
#pragma unroll
    for (int j = 0; j < 4; ++j) {
        const int col = j * 16 + lr;
        const float bb = bias[col];
#pragma unroll
        for (int r = 0; r < 4; ++r) {
            int row = rbase + r;
            if (row < N_NODES) Hbf[row * 64 + col] = bf1(acc[j][r] + bb);
        }
    }
}

// ---------------- CSR gather SpMM, 4 edge-groups per row, weight-on-the-fly ----------
// out[row] = dinv[row] * ( dinv[row]*H[row] + sum_e dinv[dst]*H[dst] ).
// Each row is handled by 4*LPR lanes: group g takes edges e0+g, e0+g+4, ... (scalar,
// uniform per group); per iter 4 gathers in flight per lane. Partials combined with
// two shfl_xor steps (LPR, 2*LPR) — no LDS, no barrier. Grids divide N exactly.
template <int C, bool OUT_BF16>
__global__ __launch_bounds__(256) void spmm_bf16_kernel(const int* __restrict__ rowptr,
                                                        const int* __restrict__ edst,
                                                        const float* __restrict__ dinv,
                                                        const uint* __restrict__ H,
                                                        void* __restrict__ outv) {
    constexpr int LPR = C / 8;        // data lanes per row
    constexpr int TPR = LPR * 4;      // threads per row (4 edge groups)
    constexpr int RPB = 256 / TPR;    // rows per block
    constexpr int US  = C / 2;        // uint row stride
    const int t = threadIdx.x;
    const int lane = t % LPR;
    const int g = (t / LPR) & 3;      // edge group
    const int row = blockIdx.x * RPB + t / TPR;
    const int cu = lane * 4;
    const float di = dinv[row];

    float acc[8];
#pragma unroll
    for (int j = 0; j < 8; ++j) acc[j] = 0.f;
    if (g == 0) {                      // self term, pre-scaled by 1/di
        uint4 hv = *(const uint4*)&H[row * US + cu];
        acc8(acc, hv, di);
    }
    const int e0 = rowptr[row], e1 = rowptr[row + 1];
    int e = e0 + g;
    for (; e + 12 < e1; e += 16) {     // 4 edges per group per iter
        int d0 = edst[e], d1 = edst[e + 4], d2 = edst[e + 8], d3 = edst[e + 12];
        float w0 = dinv[d0], w1 = dinv[d1], w2 = dinv[d2], w3 = dinv[d3];
        uint4 h0 = *(const uint4*)&H[d0 * US + cu];
        uint4 h1 = *(const uint4*)&H[d1 * US + cu];
        uint4 h2 = *(const uint4*)&H[d2 * US + cu];
        uint4 h3 = *(const uint4*)&H[d3 * US + cu];
        acc8(acc, h0, w0);
        acc8(acc, h1, w1);
        acc8(acc, h2, w2);
        acc8(acc, h3, w3);
    }
    for (; e < e1; e += 4) {
        int d = edst[e];
        float w = dinv[d];
        uint4 h = *(const uint4*)&H[d * US + cu];
        acc8(acc, h, w);
    }
    // combine the four edge groups (tree over lane^LPR then lane^2LPR)
#pragma unroll
    for (int j = 0; j < 8; ++j) acc[j] += __shfl_xor(acc[j], LPR, 64);
#pragma unroll
    for (int j = 0; j < 8; ++j) acc[j] += __shfl_xor(acc[j], 2 * LPR, 64);
    if (g != 0) return;
    if (OUT_BF16) {
        uint4 o;
        o.x = pack_bf2(acc[0] * di, acc[1] * di);
        o.y = pack_bf2(acc[2] * di, acc[3] * di);
        o.z = pack_bf2(acc[4] * di, acc[5] * di);
        o.w = pack_bf2(acc[6] * di, acc[7] * di);
        *(uint4*)&((uint*)outv)[row * US + cu] = o;
    } else {
        float* out = (float*)outv;
        *(float4*)&out[row * C + lane * 8] =
            make_float4(acc[0] * di, acc[1] * di, acc[2] * di, acc[3] * di);
        *(float4*)&out[row * C + lane * 8 + 4] =
            make_float4(acc[4] * di, acc[5] * di, acc[6] * di, acc[7] * di);
    }
}

// ---------------- BN statistics over bf16 h1agg ----------------
__global__ __launch_bounds__(256) void bn_stats_kernel(const uint* __restrict__ H,
                                                       float* __restrict__ sum,
                                                       float* __restrict__ sumsq) {
    int uc = threadIdx.x & 63;       // uint column (2 channels)
    int quarter = threadIdx.x >> 6;
    const int stride = gridDim.x * 4;
    float s0 = 0.f, q0 = 0.f, s1 = 0.f, q1 = 0.f;
    for (int r = blockIdx.x * 4 + quarter; r < N_NODES; r += stride) {
        uint u = H[r * 64 + uc];
        float a = bfl(u), b = bfh(u);
        s0 += a; q0 += a * a;
        s1 += b; q1 += b * b;
    }
    __shared__ float red[4][256];
    red[0][threadIdx.x] = s0; red[1][threadIdx.x] = q0;
    red[2][threadIdx.x] = s1; red[3][threadIdx.x] = q1;
    __syncthreads();
    if (quarter == 0) {
        float ts0 = 0.f, tq0 = 0.f, ts1 = 0.f, tq1 = 0.f;
#pragma unroll
        for (int k = 0; k < 4; ++k) {
            ts0 += red[0][k * 64 + uc]; tq0 += red[1][k * 64 + uc];
            ts1 += red[2][k * 64 + uc]; tq1 += red[3][k * 64 + uc];
        }
        atomicAdd(&sum[2 * uc], ts0);
        atomicAdd(&sum[2 * uc + 1], ts1);
        atomicAdd(&sumsq[2 * uc], tq0);
        atomicAdd(&sumsq[2 * uc + 1], tq1);
    }
}

extern "C" void kernel_launch(void* const* d_in, const int* in_sizes, int n_in,
                              void* d_out, int out_size, void* d_ws, size_t ws_size,
                              hipStream_t stream) {
    const float* x     = (const float*)d_in[0];
    const int*   ei    = (const int*)d_in[1];
    const float* W1    = (const float*)d_in[2];
    const float* b1    = (const float*)d_in[3];
    const float* gamma = (const float*)d_in[4];
    const float* beta  = (const float*)d_in[5];
    const float* W2    = (const float*)d_in[6];
    const float* b2    = (const float*)d_in[7];
    float* out = (float*)d_out;
    const int* src = ei;
    const int* dst = ei + N_EDGES;

    // ---- workspace layout (4-byte words) ----
    float* ws     = (float*)d_ws;
    float* dinv   = ws;                              // NPAD
    float* stats  = ws + NPAD;                       // 256 (sum 128 + sumsq 128)
    int*   psum   = (int*)(ws + NPAD + 512);         // 128
    int*   rowcnt = psum + 128;                      // NPAD
    int*   rowptr = rowcnt + NPAD;                   // NPAD
    float* big    = (float*)(rowptr + NPAD);
    // BIG region (word offsets), lifetime-disjoint aliases:
    //   edst     @ 0         [0.8M]     (fill -> spmms; dst-only, 4 B/edge)
    //   part_cnt @ 1.6M      [1.05M]    (8-bit; read by cursor blocks in cursor_gemm1)
    //   part_deg @ 3.7M      [1.05M]    (8-bit; dead after reduce_scan)
    //   pre      @ 5.8M      [2.1M]     (ushort prefixes; written by cursor blocks)
    //   W1t/W2t  @ 10.0M     [12K]
    //   h1bf     @ 12.0M     [3.2M]     (VIRGIN region: gemm1 blocks write while cursor
    //                                    blocks read part_cnt/write pre — round-10 crash
    //                                    was h1bf aliasing part_cnt)
    //   h1agg    @ 15.2M     [1.6M]     (spmm1 bf16 out)
    //   h2bf     @ 12.0M                (aliases h1bf; h1bf dead after spmm1)
    int*    edst     = (int*)big;
    uchar*  part_cnt = (uchar*)(big + 1600000);
    uchar*  part_deg = (uchar*)(big + 3700000);
    ushort* pre      = (ushort*)(big + 5800000);
    uint*   W1t      = (uint*)(big + 10000000);
    uint*   W2t      = W1t + 8192;
    ushort* h1bf     = (ushort*)(big + 12000000);
    uint*   h1agg    = (uint*)(big + 15200000);      // bf16 x128, packed pairs
    ushort* h2bf     = h1bf;                         // 64ch, fits in h1bf region
    float* sum    = stats;
    float* sumsq  = stats + 128;

    count_hist_kernel<<<NB_FILL + 1, 1024, 0, stream>>>(src, dst, W1, W2, W1t, W2t,
                                                        part_cnt, part_deg);
    reduce_scan_kernel<<<SCAN_BLOCKS, 256, 0, stream>>>(part_deg, part_cnt, dinv, rowcnt,
                                                        rowptr, psum, stats);
    cursor_gemm1_kernel<<<SCAN_BLOCKS + NB_G1, 256, 0, stream>>>(rowcnt, rowptr, psum,
                                                                 part_cnt, pre, x, W1t, b1,
                                                                 h1bf);
    fill_lds_kernel<<<NB_FILL, 1024, 0, stream>>>(src, dst, rowptr, pre, edst);

    spmm_bf16_kernel<128, true><<<N_NODES / 4, 256, 0, stream>>>(
        rowptr, edst, dinv, (const uint*)h1bf, (void*)h1agg);

    bn_stats_kernel<<<250, 256, 0, stream>>>(h1agg, sum, sumsq);

    gemm2_mfma_kernel<<<(N_NODES + 63) / 64, 256, 0, stream>>>(h1agg, W2t, b2, sum, sumsq,
                                                               gamma, beta, h2bf);

    spmm_bf16_kernel<64, false><<<N_NODES / 8, 256, 0, stream>>>(
        rowptr, edst, dinv, (const uint*)h2bf, (void*)out);
}